// Round 6
// baseline (203.806 us; speedup 1.0000x reference)
//
#include <hip/hip_runtime.h>
#include <hip/hip_bf16.h>

// SGC: out = (D^-1/2 (A+I) D^-1/2)^3 X W + b
// R16: structural simplification of edge ingestion + LDS-free k_fused.
//   - Partition path: direct-ELL. Per edge one global atomicAdd(cnt[dst])
//     + one 2B store into ellu. Removes LDS staging, the 6.4MB bucket
//     (write+read), and k_build's whole re-sort pass. ELL row order was
//     already race-determined before; numerics unchanged at bf16 level.
//     ELL tail is garbage: safe — k_hop guards all tail contributions
//     arithmetically and u16 indices stay inside the >=256MB workspace.
//   - GEMM path: B-fragments read directly from Wt (32KB, L2-resident)
//     instead of a per-block 32KB LDS stage. k_fused now uses ZERO LDS ->
//     occupancy cap 4 -> 8 blocks/CU. R15 falsified the straggler theory;
//     R2 counters (Occ 15%, VALUBusy 4.8%) point at occupancy+structure.
//   - k_build replaced by streaming k_scale (dinv + Z = dinv.*Y, ~13MB).
//   Hops identical to R11/R15 (the verified 186us hop structure).

#define NFEAT 256
#define NCLS  64
#define ELLW  64       // slots per node; P(deg>=64) ~ 1e-18 for Binomial(E,1/N)
#define PCHUNK 2048    // edges per partition block

typedef __attribute__((ext_vector_type(8))) short bf16x8;
typedef __attribute__((ext_vector_type(4))) float f32x4;
typedef __attribute__((ext_vector_type(4))) int   i32x4;
typedef __attribute__((ext_vector_type(4))) unsigned int u32x4;

__device__ __forceinline__ float bf2f(unsigned int u) {
    return __uint_as_float(u << 16);
}
__device__ __forceinline__ float bf2f_hi(unsigned int u) {
    return __uint_as_float(u & 0xffff0000u);
}
__device__ __forceinline__ unsigned short f2bf(float f) {
    unsigned int u = __float_as_uint(f);
    unsigned int r = u + 0x7fffu + ((u >> 16) & 1u);  // RNE
    return (unsigned short)(r >> 16);
}
__device__ __forceinline__ unsigned int pack2bf(float a, float b) {
    return (unsigned int)f2bf(a) | ((unsigned int)f2bf(b) << 16);
}

// ---------- fused setup: block0 edge-dtype detect; block1 float detect +
// ---------- bias convert; blocks 2.. W convert (local probe) + zero cnt ----
__global__ void k_setup(const void* ei, int twoE, int nnodes,
                        const unsigned int* __restrict__ x, int nwords,
                        const void* __restrict__ Wg, const void* __restrict__ Bg,
                        int* flag, int* fflag, int* __restrict__ cnt, int N,
                        unsigned short* __restrict__ Wt, float* __restrict__ bc) {
    __shared__ int acc;
    const int t = threadIdx.x;
    const int b = blockIdx.x;
    if (t == 0) acc = 0;
    __syncthreads();

    if (b == 0) {
        const long long* p = (const long long*)ei;
        int nchk = 2048;
        if (nchk > twoE / 2) nchk = twoE / 2;
        int bad = 0;
        for (int i = t; i < nchk; i += 256) {
            long long v = p[i];
            if (v < 0 || v >= (long long)nnodes) bad++;
        }
        if (bad) atomicAdd(&acc, bad);
        __syncthreads();
        if (t == 0) *flag = (acc == 0) ? 1 : 0;  // 1 = int64
        return;
    }

    // float dtype probe (local to each block; x is same dtype as W/b)
    int lim = nwords < 4096 ? nwords : 4096;
    int wild = 0;
    for (int i = t; i < lim; i += 256) {
        unsigned int lo = x[i] & 0xffffu;
        unsigned int expf = (lo >> 7) & 0xffu;
        if (expf >= 0x97u) wild++;  // fp32 mantissa noise read as bf16
    }
    if (wild) atomicAdd(&acc, wild);
    __syncthreads();
    const bool isbf = (acc < 8);

    if (b == 1) {
        if (t == 0) *fflag = isbf ? 1 : 0;
        if (t < NCLS) {
            bc[t] = isbf ? bf2f(((const unsigned short*)Bg)[t])
                         : ((const float*)Bg)[t];
        }
        return;
    }

    // W -> bf16 transposed [n][k]  (64 blocks: b = 2..65)
    int i = (b - 2) * 256 + t;
    if (i < NFEAT * NCLS) {
        int n = i >> 8, k = i & 255;  // Wt[n][k] = W[k][n]
        Wt[i] = isbf ? ((const unsigned short*)Wg)[k * NCLS + n]
                     : f2bf(((const float*)Wg)[k * NCLS + n]);
    }
    // zero cnt, striped across the same 64 blocks
    for (int j = (b - 2) * 256 + t; j < N; j += 64 * 256) cnt[j] = 0;
}

// ---------- fused: [0, npart) = direct-ELL partition, [npart, ..) = GEMM ----
// ZERO LDS in both paths -> 8 blocks/CU occupancy.
__launch_bounds__(256)
__global__ void k_fused(const void* __restrict__ Xg,
                        const unsigned short* __restrict__ Wt,  // [n][k] bf16
                        unsigned short* __restrict__ Yb,        // out bf16 [N][64]
                        int N, const int* __restrict__ fflag,
                        const void* __restrict__ ei, int E, const int* __restrict__ flag,
                        unsigned short* __restrict__ ellu, int* __restrict__ cnt,
                        int npart) {
    const int t = threadIdx.x;

    if (blockIdx.x < npart) {
        // ---------------- direct-ELL partition ----------------
        const int bstart = blockIdx.x * PCHUNK;
        const bool is64 = (*flag != 0);
#pragma unroll
        for (int i = 0; i < PCHUNK / 256; ++i) {
            int e = bstart + i * 256 + t;
            if (e < E) {
                int ss, dd;
                if (is64) {
                    ss = (int)__builtin_nontemporal_load((const long long*)ei + e);
                    dd = (int)__builtin_nontemporal_load((const long long*)ei + E + e);
                } else {
                    ss = __builtin_nontemporal_load((const int*)ei + e);
                    dd = __builtin_nontemporal_load((const int*)ei + E + e);
                }
                int r = atomicAdd(&cnt[dd], 1);
                if (r < ELLW)
                    ellu[(size_t)dd * ELLW + r] = (unsigned short)ss;
            }
        }
        return;
    }

    // ---------------- GEMM path (B direct from L2-resident Wt) ----------------
    const int gb = blockIdx.x - npart;
    const int wv = t >> 6, lane = t & 63;
    const int m = lane & 15, q = lane >> 4;
    const int row = gb * 64 + wv * 16 + m;
    const bool rowok = row < N;
    const bool isbf = (*fflag != 0);

    // lane's B base: n = tile*16 + (lane&15), k = ks*32 + (lane>>4)*8
    const unsigned short* wl = Wt + (size_t)(lane & 15) * 256 + (lane >> 4) * 8;

    f32x4 acc0 = {0.f, 0.f, 0.f, 0.f};
    f32x4 acc1 = {0.f, 0.f, 0.f, 0.f};
    f32x4 acc2 = {0.f, 0.f, 0.f, 0.f};
    f32x4 acc3 = {0.f, 0.f, 0.f, 0.f};

    for (int ks = 0; ks < 8; ++ks) {
        const int kk = ks * 32 + q * 8;
        bf16x8 af = {0, 0, 0, 0, 0, 0, 0, 0};
        if (rowok) {
            if (isbf) {
                const i32x4* xp = (const i32x4*)((const unsigned short*)Xg + (size_t)row * NFEAT + kk);
                i32x4 raw = __builtin_nontemporal_load(xp);
#pragma unroll
                for (int h = 0; h < 4; ++h) {
                    af[2 * h]     = (short)(raw[h] & 0xffff);
                    af[2 * h + 1] = (short)(((unsigned int)raw[h]) >> 16);
                }
            } else {
                const i32x4* xp = (const i32x4*)((const float*)Xg + (size_t)row * NFEAT + kk);
                i32x4 r0 = __builtin_nontemporal_load(xp);
                i32x4 r1 = __builtin_nontemporal_load(xp + 1);
#pragma unroll
                for (int h = 0; h < 4; ++h) {
                    af[h]     = (short)f2bf(__int_as_float(r0[h]));
                    af[h + 4] = (short)f2bf(__int_as_float(r1[h]));
                }
            }
        }
        const unsigned short* wb = wl + ks * 32;
        bf16x8 b0 = *(const bf16x8*)(wb);              // n tile 0
        bf16x8 b1 = *(const bf16x8*)(wb + 16 * 256);   // n tile 1
        bf16x8 b2 = *(const bf16x8*)(wb + 32 * 256);   // n tile 2
        bf16x8 b3 = *(const bf16x8*)(wb + 48 * 256);   // n tile 3
        acc0 = __builtin_amdgcn_mfma_f32_16x16x32_bf16(af, b0, acc0, 0, 0, 0);
        acc1 = __builtin_amdgcn_mfma_f32_16x16x32_bf16(af, b1, acc1, 0, 0, 0);
        acc2 = __builtin_amdgcn_mfma_f32_16x16x32_bf16(af, b2, acc2, 0, 0, 0);
        acc3 = __builtin_amdgcn_mfma_f32_16x16x32_bf16(af, b3, acc3, 0, 0, 0);
    }

    // C/D layout: col = lane&15, row = q*4 + reg
    const int rowbase = gb * 64 + wv * 16 + q * 4;
#pragma unroll
    for (int i = 0; i < 4; ++i) {
        int gr = rowbase + i;
        if (gr < N) {
            unsigned short* yp = Yb + (size_t)gr * NCLS + m;
            yp[0]  = f2bf(acc0[i]);
            yp[16] = f2bf(acc1[i]);
            yp[32] = f2bf(acc2[i]);
            yp[48] = f2bf(acc3[i]);
        }
    }
}

// ---------- pass 2 (streaming): dinv = rsqrt(cnt+1); clamp cnt; Z = dinv.*Y ----
__launch_bounds__(256)
__global__ void k_scale(int* __restrict__ cnt, float* __restrict__ dinv,
                        const unsigned int* __restrict__ Yb,  // [N][32] u32 view
                        unsigned int* __restrict__ Z,         // [N][32] u32 view
                        int N) {
    int w = blockIdx.x * 256 + threadIdx.x;
    if (w >= N * 32) return;
    int node = w >> 5, l = w & 31;
    int c = cnt[node];
    float dv = rsqrtf((float)(c + 1));  // +1 = self loop
    unsigned int y = Yb[w];
    Z[w] = pack2bf(dv * bf2f(y), dv * bf2f_hi(y));
    if (l == 0) {
        dinv[node] = dv;
        if (c > ELLW) cnt[node] = ELLW;  // write only when it differs (deg>64)
    }
}

// ---------- hop: 32-lane node-groups, lane = feature pair (u32 = 2 bf16) ----
// Zout[d] = dinv_d^2 * (Z[d] + sum_s Z[s]);  last hop: out = dinv_d*(...) + b.
__launch_bounds__(256)
__global__ void k_hop(const unsigned int* __restrict__ Zin,  // [N][32] u32
                      const unsigned short* __restrict__ ellu,
                      const int* __restrict__ cnt, const float* __restrict__ dinv,
                      unsigned int* __restrict__ Zout,       // hops 1-2
                      float* __restrict__ outf,              // last hop [N][64] fp32
                      const float* __restrict__ bc, int N) {
    int node = blockIdx.x * 8 + (threadIdx.x >> 5);
    if (node >= N) return;
    const int l = threadIdx.x & 31;
    const int deg = cnt[node];   // clamped <= 64 by k_scale
    const float dn = dinv[node];
    unsigned int zself = Zin[(size_t)node * 32 + l];
    float a0 = bf2f(zself), a1 = 0.f, a2 = 0.f, a3 = 0.f;       // lo chains
    float b0 = bf2f_hi(zself), b1 = 0.f, b2 = 0.f, b3 = 0.f;    // hi chains
    const unsigned short* erow = ellu + (size_t)node * ELLW;
    int e = 0;
    for (; e + 16 <= deg; e += 16) {
        u32x4 ua = *(const u32x4*)(erow + e);      // 8 edges (broadcast 16B)
        u32x4 ub = *(const u32x4*)(erow + e + 8);  // 8 edges
        int s[16];
#pragma unroll
        for (int i = 0; i < 4; ++i) {
            s[2 * i]     = (int)(ua[i] & 0xffffu);
            s[2 * i + 1] = (int)(ua[i] >> 16);
            s[2 * i + 8] = (int)(ub[i] & 0xffffu);
            s[2 * i + 9] = (int)(ub[i] >> 16);
        }
        unsigned int z[16];
#pragma unroll
        for (int i = 0; i < 16; ++i) z[i] = Zin[(size_t)s[i] * 32 + l];
#pragma unroll
        for (int i = 0; i < 16; i += 4) {
            a0 += bf2f(z[i]);     b0 += bf2f_hi(z[i]);
            a1 += bf2f(z[i + 1]); b1 += bf2f_hi(z[i + 1]);
            a2 += bf2f(z[i + 2]); b2 += bf2f_hi(z[i + 2]);
            a3 += bf2f(z[i + 3]); b3 += bf2f_hi(z[i + 3]);
        }
    }
    if (e < deg) {  // guarded tail batch; garbage ELL entries masked by guards
        u32x4 ua = *(const u32x4*)(erow + e);
        u32x4 ub = *(const u32x4*)(erow + e + 8);
        int s[16];
#pragma unroll
        for (int i = 0; i < 4; ++i) {
            s[2 * i]     = (int)(ua[i] & 0xffffu);
            s[2 * i + 1] = (int)(ua[i] >> 16);
            s[2 * i + 8] = (int)(ub[i] & 0xffffu);
            s[2 * i + 9] = (int)(ub[i] >> 16);
        }
        unsigned int z[16];
#pragma unroll
        for (int i = 0; i < 16; ++i) z[i] = Zin[(size_t)s[i] * 32 + l];
#pragma unroll
        for (int i = 0; i < 16; i += 4) {
            bool g0 = (e + i < deg), g1 = (e + i + 1 < deg);
            bool g2 = (e + i + 2 < deg), g3 = (e + i + 3 < deg);
            a0 += g0 ? bf2f(z[i]) : 0.f;     b0 += g0 ? bf2f_hi(z[i]) : 0.f;
            a1 += g1 ? bf2f(z[i + 1]) : 0.f; b1 += g1 ? bf2f_hi(z[i + 1]) : 0.f;
            a2 += g2 ? bf2f(z[i + 2]) : 0.f; b2 += g2 ? bf2f_hi(z[i + 2]) : 0.f;
            a3 += g3 ? bf2f(z[i + 3]) : 0.f; b3 += g3 ? bf2f_hi(z[i + 3]) : 0.f;
        }
    }
    float lo = (a0 + a1) + (a2 + a3);
    float hi = (b0 + b1) + (b2 + b3);
    if (outf) {
        float2 bv = *(const float2*)(bc + 2 * l);
        float2 o = make_float2(dn * lo + bv.x, dn * hi + bv.y);
        *(float2*)(outf + (size_t)node * NCLS + 2 * l) = o;
    } else {
        float d2 = dn * dn;
        Zout[(size_t)node * 32 + l] = pack2bf(d2 * lo, d2 * hi);
    }
}

extern "C" void kernel_launch(void* const* d_in, const int* in_sizes, int n_in,
                              void* d_out, int out_size, void* d_ws, size_t ws_size,
                              hipStream_t stream) {
    const void* X  = d_in[0];
    const void* EI = d_in[1];
    const void* W  = d_in[2];
    const void* B  = d_in[3];
    float* out = (float*)d_out;

    const int N = in_sizes[0] / NFEAT;  // 50000
    const int twoE = in_sizes[1];       // 1,600,000
    const int E = twoE / 2;             // 800,000

    // ---- carve workspace (256B aligned) ----
    char* p = (char*)d_ws;
    auto alloc = [&](size_t bytes) -> char* {
        char* q = p;
        p += (bytes + 255) & ~(size_t)255;
        return q;
    };
    int*   flag   = (int*)alloc(4);
    int*   fflag  = (int*)alloc(4);
    int*   cnt    = (int*)alloc((size_t)N * 4);
    float* dinv   = (float*)alloc((size_t)N * 4);
    unsigned short* Wt = (unsigned short*)alloc((size_t)NFEAT * NCLS * 2);
    float* bc     = (float*)alloc((size_t)NCLS * 4);
    unsigned short* ellu = (unsigned short*)alloc((size_t)N * ELLW * 2);  // 6.4 MB
    unsigned short* Y0 = (unsigned short*)alloc((size_t)N * NCLS * 2);    // 6.4 MB
    unsigned short* Z0 = (unsigned short*)alloc((size_t)N * NCLS * 2);    // 6.4 MB
    unsigned short* Z1 = (unsigned short*)alloc((size_t)N * NCLS * 2);    // 6.4 MB

    k_setup<<<2 + NFEAT * NCLS / 256, 256, 0, stream>>>(
        EI, twoE, N, (const unsigned int*)X, in_sizes[0] / 2,
        W, B, flag, fflag, cnt, N, Wt, bc);

    const int ngemm = (N + 63) / 64;              // 782
    const int npart = (E + PCHUNK - 1) / PCHUNK;  // 391
    k_fused<<<ngemm + npart, 256, 0, stream>>>(X, Wt, Y0, N, fflag,
                                               EI, E, flag, ellu, cnt, npart);

    k_scale<<<(N * 32 + 255) / 256, 256, 0, stream>>>(cnt, dinv,
                                                      (const unsigned int*)Y0,
                                                      (unsigned int*)Z0, N);

    const int nb_h = (N + 7) / 8;  // 6250
    k_hop<<<nb_h, 256, 0, stream>>>((const unsigned int*)Z0, ellu, cnt, dinv,
                                    (unsigned int*)Z1, nullptr, bc, N);
    k_hop<<<nb_h, 256, 0, stream>>>((const unsigned int*)Z1, ellu, cnt, dinv,
                                    (unsigned int*)Z0, nullptr, bc, N);
    k_hop<<<nb_h, 256, 0, stream>>>((const unsigned int*)Z0, ellu, cnt, dinv,
                                    nullptr, out, bc, N);
}

// Round 7
// 189.329 us; speedup vs baseline: 1.0765x; 1.0765x over previous
//
#include <hip/hip_runtime.h>
#include <hip/hip_bf16.h>

// SGC: out = (D^-1/2 (A+I) D^-1/2)^3 X W + b
// R17: latency fixes for k_fused; ingestion reverted to bucket+k_build
//   (R16 showed direct-ELL scatter = 51.7MB write-amp; bucket keeps ELL
//   writes coalesced).
//   - LDS shrunk 37.5KB -> 13KB (stage sized to PCHUNK=2048; R15 kept the
//     8192-entry buffer by mistake) -> 8 blocks/CU for both paths.
//   - GEMM path: zero LDS use. B-fragments direct from L2-resident Wt
//     (mapping verified by R16 pass). A-row preloaded as 8 independent
//     nontemporal loads BEFORE the MFMA loop (was 8 serial HBM round-trips
//     -> latency-bound at 943 GB/s, Occ 15%, everything idle).
//   - Partition/build/hops bit-identical to R15 (186us verified).

#define NFEAT 256
#define NCLS  64
#define ELLW  64       // slots per node; P(deg>=64) ~ 1e-18 for Binomial(E,1/N)
#define NPB   128      // nodes per bucket (dst >> 7)
#define BCAP  4096     // per-bucket edge capacity (mean ~2048, sigma ~45)
#define PCHUNK 2048    // edges per partition block

typedef __attribute__((ext_vector_type(8))) short bf16x8;
typedef __attribute__((ext_vector_type(4))) float f32x4;
typedef __attribute__((ext_vector_type(4))) int   i32x4;
typedef __attribute__((ext_vector_type(4))) unsigned int u32x4;

__device__ __forceinline__ float bf2f(unsigned int u) {
    return __uint_as_float(u << 16);
}
__device__ __forceinline__ float bf2f_hi(unsigned int u) {
    return __uint_as_float(u & 0xffff0000u);
}
__device__ __forceinline__ unsigned short f2bf(float f) {
    unsigned int u = __float_as_uint(f);
    unsigned int r = u + 0x7fffu + ((u >> 16) & 1u);  // RNE
    return (unsigned short)(r >> 16);
}
__device__ __forceinline__ unsigned int pack2bf(float a, float b) {
    return (unsigned int)f2bf(a) | ((unsigned int)f2bf(b) << 16);
}

// ---------- fused setup: block0 edge-dtype detect; block1 float detect +
// ---------- bias convert + gcur zero; blocks 2.. W convert (local probe) ----
__global__ void k_setup(const void* ei, int twoE, int nnodes,
                        const unsigned int* __restrict__ x, int nwords,
                        const void* __restrict__ Wg, const void* __restrict__ Bg,
                        int* flag, int* fflag, int* gcur, int NB,
                        unsigned short* __restrict__ Wt, float* __restrict__ bc) {
    __shared__ int acc;
    const int t = threadIdx.x;
    const int b = blockIdx.x;
    if (t == 0) acc = 0;
    __syncthreads();

    if (b == 0) {
        const long long* p = (const long long*)ei;
        int nchk = 2048;
        if (nchk > twoE / 2) nchk = twoE / 2;
        int bad = 0;
        for (int i = t; i < nchk; i += 256) {
            long long v = p[i];
            if (v < 0 || v >= (long long)nnodes) bad++;
        }
        if (bad) atomicAdd(&acc, bad);
        __syncthreads();
        if (t == 0) *flag = (acc == 0) ? 1 : 0;  // 1 = int64
        return;
    }

    // float dtype probe (local to each block; x is same dtype as W/b)
    int lim = nwords < 4096 ? nwords : 4096;
    int wild = 0;
    for (int i = t; i < lim; i += 256) {
        unsigned int lo = x[i] & 0xffffu;
        unsigned int expf = (lo >> 7) & 0xffu;
        if (expf >= 0x97u) wild++;  // fp32 mantissa noise read as bf16
    }
    if (wild) atomicAdd(&acc, wild);
    __syncthreads();
    const bool isbf = (acc < 8);

    if (b == 1) {
        if (t == 0) *fflag = isbf ? 1 : 0;
        for (int i = t; i < NB; i += 256) gcur[i] = 0;
        if (t < NCLS) {
            bc[t] = isbf ? bf2f(((const unsigned short*)Bg)[t])
                         : ((const float*)Bg)[t];
        }
        return;
    }

    // W -> bf16 transposed [n][k]
    int i = (b - 2) * 256 + t;
    if (i < NFEAT * NCLS) {
        int n = i >> 8, k = i & 255;  // Wt[n][k] = W[k][n]
        Wt[i] = isbf ? ((const unsigned short*)Wg)[k * NCLS + n]
                     : f2bf(((const float*)Wg)[k * NCLS + n]);
    }
}

// ---------- fused: [0, npart) = partition blocks, [npart, ..) = GEMM ----
// LDS = 13KB (partition stage+hist only); GEMM path uses no LDS.
__launch_bounds__(256)
__global__ void k_fused(const void* __restrict__ Xg,
                        const unsigned short* __restrict__ Wt,  // [n][k] bf16
                        unsigned short* __restrict__ Yb,        // out bf16 [N][64]
                        int N, int NB, const int* __restrict__ fflag,
                        const void* __restrict__ ei, int E, const int* __restrict__ flag,
                        unsigned int* __restrict__ bucket, int* __restrict__ gcur,
                        int npart) {
    __shared__ char smem[PCHUNK * 4 + 3 * 1600];  // 13 KB
    const int t = threadIdx.x;

    if (blockIdx.x < npart) {
        // ---------------- partition path ----------------
        unsigned int* stage = (unsigned int*)smem;       // PCHUNK entries
        int* hist = (int*)(smem + PCHUNK * 4);           // [400]
        int* base = hist + 400;
        int* rank = base + 400;
        for (int b = t; b < NB; b += 256) { hist[b] = 0; rank[b] = 0; }
        __syncthreads();
        const int bstart = blockIdx.x * PCHUNK;
        const bool is64 = (*flag != 0);
#pragma unroll
        for (int i = 0; i < PCHUNK / 256; ++i) {
            int e = bstart + i * 256 + t;
            unsigned int v = 0xFFFFFFFFu;  // sentinel
            if (e < E) {
                int ss, dd;
                if (is64) {
                    ss = (int)__builtin_nontemporal_load((const long long*)ei + e);
                    dd = (int)__builtin_nontemporal_load((const long long*)ei + E + e);
                } else {
                    ss = __builtin_nontemporal_load((const int*)ei + e);
                    dd = __builtin_nontemporal_load((const int*)ei + E + e);
                }
                int j = dd >> 7;
                atomicAdd(&hist[j], 1);
                v = ((unsigned int)j << 23) | ((unsigned int)(dd & 127) << 16) |
                    (unsigned int)ss;
            }
            stage[i * 256 + t] = v;
        }
        __syncthreads();
        for (int b = t; b < NB; b += 256) base[b] = atomicAdd(&gcur[b], hist[b]);
        __syncthreads();
#pragma unroll
        for (int i = 0; i < PCHUNK / 256; ++i) {
            unsigned int v = stage[i * 256 + t];
            if (v != 0xFFFFFFFFu) {
                int j = v >> 23;
                int r = atomicAdd(&rank[j], 1);
                int pos = base[j] + r;
                if (pos < BCAP)
                    bucket[(size_t)j * BCAP + pos] = v & 0x7FFFFFu;  // (ld<<16)|s
            }
        }
        return;
    }

    // ---------------- GEMM path (no LDS; B direct from L2-resident Wt) ----
    const int gb = blockIdx.x - npart;
    const int wv = t >> 6, lane = t & 63;
    const int m = lane & 15, q = lane >> 4;
    const int row = gb * 64 + wv * 16 + m;
    const bool rowok = row < N;
    const bool isbf = (*fflag != 0);

    // Preload the lane's whole A-slice: 8 independent loads in flight.
    i32x4 ra[8], rb[8];
    if (rowok) {
        if (isbf) {
#pragma unroll
            for (int ks = 0; ks < 8; ++ks) {
                const i32x4* xp = (const i32x4*)((const unsigned short*)Xg +
                                                 (size_t)row * NFEAT + ks * 32 + q * 8);
                ra[ks] = __builtin_nontemporal_load(xp);
            }
        } else {
#pragma unroll
            for (int ks = 0; ks < 8; ++ks) {
                const i32x4* xp = (const i32x4*)((const float*)Xg +
                                                 (size_t)row * NFEAT + ks * 32 + q * 8);
                ra[ks] = __builtin_nontemporal_load(xp);
                rb[ks] = __builtin_nontemporal_load(xp + 1);
            }
        }
    }

    // lane's B base: n = tile*16 + (lane&15), k = ks*32 + (lane>>4)*8
    const unsigned short* wl = Wt + (size_t)(lane & 15) * 256 + (lane >> 4) * 8;

    f32x4 acc0 = {0.f, 0.f, 0.f, 0.f};
    f32x4 acc1 = {0.f, 0.f, 0.f, 0.f};
    f32x4 acc2 = {0.f, 0.f, 0.f, 0.f};
    f32x4 acc3 = {0.f, 0.f, 0.f, 0.f};

#pragma unroll
    for (int ks = 0; ks < 8; ++ks) {
        bf16x8 af = {0, 0, 0, 0, 0, 0, 0, 0};
        if (rowok) {
            if (isbf) {
                i32x4 raw = ra[ks];
#pragma unroll
                for (int h = 0; h < 4; ++h) {
                    af[2 * h]     = (short)(raw[h] & 0xffff);
                    af[2 * h + 1] = (short)(((unsigned int)raw[h]) >> 16);
                }
            } else {
                i32x4 r0 = ra[ks], r1 = rb[ks];
#pragma unroll
                for (int h = 0; h < 4; ++h) {
                    af[h]     = (short)f2bf(__int_as_float(r0[h]));
                    af[h + 4] = (short)f2bf(__int_as_float(r1[h]));
                }
            }
        }
        const unsigned short* wb = wl + ks * 32;
        bf16x8 b0 = *(const bf16x8*)(wb);              // n tile 0
        bf16x8 b1 = *(const bf16x8*)(wb + 16 * 256);   // n tile 1
        bf16x8 b2 = *(const bf16x8*)(wb + 32 * 256);   // n tile 2
        bf16x8 b3 = *(const bf16x8*)(wb + 48 * 256);   // n tile 3
        acc0 = __builtin_amdgcn_mfma_f32_16x16x32_bf16(af, b0, acc0, 0, 0, 0);
        acc1 = __builtin_amdgcn_mfma_f32_16x16x32_bf16(af, b1, acc1, 0, 0, 0);
        acc2 = __builtin_amdgcn_mfma_f32_16x16x32_bf16(af, b2, acc2, 0, 0, 0);
        acc3 = __builtin_amdgcn_mfma_f32_16x16x32_bf16(af, b3, acc3, 0, 0, 0);
    }

    // C/D layout: col = lane&15, row = q*4 + reg
    const int rowbase = gb * 64 + wv * 16 + q * 4;
#pragma unroll
    for (int i = 0; i < 4; ++i) {
        int gr = rowbase + i;
        if (gr < N) {
            unsigned short* yp = Yb + (size_t)gr * NCLS + m;
            yp[0]  = f2bf(acc0[i]);
            yp[16] = f2bf(acc1[i]);
            yp[32] = f2bf(acc2[i]);
            yp[48] = f2bf(acc3[i]);
        }
    }
}

// ---------- pass 2: one block per bucket; build 128-node ELL slab in LDS,
// ---------- dump ELL+cnt+dinv coalesced; Z = dinv .* Y (bf16 [N][64]) ----------
__launch_bounds__(256)
__global__ void k_build(const unsigned int* __restrict__ bucket,
                        const int* __restrict__ gcur,
                        int* __restrict__ cnt, float* __restrict__ dinv,
                        unsigned short* __restrict__ ellu,
                        const unsigned int* __restrict__ Yb,  // [N][32] u32 view
                        unsigned int* __restrict__ Z,         // [N][32] u32 view
                        int N) {
    __shared__ unsigned short ellb[NPB * ELLW];  // 16 KB
    __shared__ int lcnt[NPB];
    __shared__ float sdinv[NPB];
    const int t = threadIdx.x;
    const int j = blockIdx.x;
    if (t < NPB) lcnt[t] = 0;
    {
        u32x4* eb4 = (u32x4*)ellb;
        u32x4 z = {0, 0, 0, 0};
        for (int i = t; i < NPB * ELLW / 8; i += 256) eb4[i] = z;
    }
    __syncthreads();
    int total = gcur[j];
    if (total > BCAP) total = BCAP;
    const unsigned int* bb = bucket + (size_t)j * BCAP;
    for (int i = t; i < total; i += 256) {
        unsigned int v = __builtin_nontemporal_load(bb + i);
        int ld = (v >> 16) & 127;
        int s = v & 0xffffu;
        int r = atomicAdd(&lcnt[ld], 1);
        if (r < ELLW) ellb[(ld << 6) + r] = (unsigned short)s;
    }
    __syncthreads();
    const int node0 = j << 7;
    if (t < NPB) {
        int node = node0 + t;
        int c = lcnt[t];
        float dv = rsqrtf((float)(c + 1));  // +1 = self loop
        sdinv[t] = dv;
        if (node < N) {
            cnt[node] = c > ELLW ? ELLW : c;
            dinv[node] = dv;
        }
    }
    __syncthreads();
    // dump ELL slab (u32x4 = 8 entries), rows 128B each
    u32x4* ellg = (u32x4*)ellu;
    const u32x4* eb = (const u32x4*)ellb;
    for (int i = t; i < NPB * (ELLW / 8); i += 256) {
        int node = node0 + (i >> 3);
        if (node < N) ellg[(size_t)node0 * 8 + i] = eb[i];
    }
    // Z = dinv .* Y (u32 = 2 bf16 feats per word)
    for (int w = t; w < NPB * 32; w += 256) {
        int nl = w >> 5, l = w & 31;
        int node = node0 + nl;
        if (node < N) {
            float dv = sdinv[nl];
            unsigned int y = Yb[(size_t)node * 32 + l];
            Z[(size_t)node * 32 + l] = pack2bf(dv * bf2f(y), dv * bf2f_hi(y));
        }
    }
}

// ---------- hop: 32-lane node-groups, lane = feature pair (u32 = 2 bf16) ----
// Zout[d] = dinv_d^2 * (Z[d] + sum_s Z[s]);  last hop: out = dinv_d*(...) + b.
__launch_bounds__(256)
__global__ void k_hop(const unsigned int* __restrict__ Zin,  // [N][32] u32
                      const unsigned short* __restrict__ ellu,
                      const int* __restrict__ cnt, const float* __restrict__ dinv,
                      unsigned int* __restrict__ Zout,       // hops 1-2
                      float* __restrict__ outf,              // last hop [N][64] fp32
                      const float* __restrict__ bc, int N) {
    int node = blockIdx.x * 8 + (threadIdx.x >> 5);
    if (node >= N) return;
    const int l = threadIdx.x & 31;
    const int deg = cnt[node];   // clamped <= 64 by k_build
    const float dn = dinv[node];
    unsigned int zself = Zin[(size_t)node * 32 + l];
    float a0 = bf2f(zself), a1 = 0.f, a2 = 0.f, a3 = 0.f;       // lo chains
    float b0 = bf2f_hi(zself), b1 = 0.f, b2 = 0.f, b3 = 0.f;    // hi chains
    const unsigned short* erow = ellu + (size_t)node * ELLW;
    int e = 0;
    for (; e + 16 <= deg; e += 16) {
        u32x4 ua = *(const u32x4*)(erow + e);      // 8 edges (broadcast 16B)
        u32x4 ub = *(const u32x4*)(erow + e + 8);  // 8 edges
        int s[16];
#pragma unroll
        for (int i = 0; i < 4; ++i) {
            s[2 * i]     = (int)(ua[i] & 0xffffu);
            s[2 * i + 1] = (int)(ua[i] >> 16);
            s[2 * i + 8] = (int)(ub[i] & 0xffffu);
            s[2 * i + 9] = (int)(ub[i] >> 16);
        }
        unsigned int z[16];
#pragma unroll
        for (int i = 0; i < 16; ++i) z[i] = Zin[(size_t)s[i] * 32 + l];
#pragma unroll
        for (int i = 0; i < 16; i += 4) {
            a0 += bf2f(z[i]);     b0 += bf2f_hi(z[i]);
            a1 += bf2f(z[i + 1]); b1 += bf2f_hi(z[i + 1]);
            a2 += bf2f(z[i + 2]); b2 += bf2f_hi(z[i + 2]);
            a3 += bf2f(z[i + 3]); b3 += bf2f_hi(z[i + 3]);
        }
    }
    if (e < deg) {  // guarded tail batch; ELL tail is zeroed -> s=0 reads safe
        u32x4 ua = *(const u32x4*)(erow + e);
        u32x4 ub = *(const u32x4*)(erow + e + 8);
        int s[16];
#pragma unroll
        for (int i = 0; i < 4; ++i) {
            s[2 * i]     = (int)(ua[i] & 0xffffu);
            s[2 * i + 1] = (int)(ua[i] >> 16);
            s[2 * i + 8] = (int)(ub[i] & 0xffffu);
            s[2 * i + 9] = (int)(ub[i] >> 16);
        }
        unsigned int z[16];
#pragma unroll
        for (int i = 0; i < 16; ++i) z[i] = Zin[(size_t)s[i] * 32 + l];
#pragma unroll
        for (int i = 0; i < 16; i += 4) {
            bool g0 = (e + i < deg), g1 = (e + i + 1 < deg);
            bool g2 = (e + i + 2 < deg), g3 = (e + i + 3 < deg);
            a0 += g0 ? bf2f(z[i]) : 0.f;     b0 += g0 ? bf2f_hi(z[i]) : 0.f;
            a1 += g1 ? bf2f(z[i + 1]) : 0.f; b1 += g1 ? bf2f_hi(z[i + 1]) : 0.f;
            a2 += g2 ? bf2f(z[i + 2]) : 0.f; b2 += g2 ? bf2f_hi(z[i + 2]) : 0.f;
            a3 += g3 ? bf2f(z[i + 3]) : 0.f; b3 += g3 ? bf2f_hi(z[i + 3]) : 0.f;
        }
    }
    float lo = (a0 + a1) + (a2 + a3);
    float hi = (b0 + b1) + (b2 + b3);
    if (outf) {
        float2 bv = *(const float2*)(bc + 2 * l);
        float2 o = make_float2(dn * lo + bv.x, dn * hi + bv.y);
        *(float2*)(outf + (size_t)node * NCLS + 2 * l) = o;
    } else {
        float d2 = dn * dn;
        Zout[(size_t)node * 32 + l] = pack2bf(d2 * lo, d2 * hi);
    }
}

extern "C" void kernel_launch(void* const* d_in, const int* in_sizes, int n_in,
                              void* d_out, int out_size, void* d_ws, size_t ws_size,
                              hipStream_t stream) {
    const void* X  = d_in[0];
    const void* EI = d_in[1];
    const void* W  = d_in[2];
    const void* B  = d_in[3];
    float* out = (float*)d_out;

    const int N = in_sizes[0] / NFEAT;  // 50000
    const int twoE = in_sizes[1];       // 1,600,000
    const int E = twoE / 2;             // 800,000
    const int NB = (N + NPB - 1) / NPB; // 391 buckets

    // ---- carve workspace (256B aligned) ----
    char* p = (char*)d_ws;
    auto alloc = [&](size_t bytes) -> char* {
        char* q = p;
        p += (bytes + 255) & ~(size_t)255;
        return q;
    };
    int*   flag   = (int*)alloc(4);
    int*   fflag  = (int*)alloc(4);
    int*   gcur   = (int*)alloc((size_t)NB * 4);
    int*   cnt    = (int*)alloc((size_t)N * 4);
    float* dinv   = (float*)alloc((size_t)N * 4);
    unsigned short* Wt = (unsigned short*)alloc((size_t)NFEAT * NCLS * 2);
    float* bc     = (float*)alloc((size_t)NCLS * 4);
    unsigned int* bucket = (unsigned int*)alloc((size_t)NB * BCAP * 4);   // 6.4 MB
    unsigned short* ellu = (unsigned short*)alloc((size_t)N * ELLW * 2);  // 6.4 MB
    unsigned short* Y0 = (unsigned short*)alloc((size_t)N * NCLS * 2);    // 6.4 MB
    unsigned short* Z0 = (unsigned short*)alloc((size_t)N * NCLS * 2);    // 6.4 MB
    unsigned short* Z1 = (unsigned short*)alloc((size_t)N * NCLS * 2);    // 6.4 MB

    k_setup<<<2 + NFEAT * NCLS / 256, 256, 0, stream>>>(
        EI, twoE, N, (const unsigned int*)X, in_sizes[0] / 2,
        W, B, flag, fflag, gcur, NB, Wt, bc);

    const int ngemm = (N + 63) / 64;              // 782
    const int npart = (E + PCHUNK - 1) / PCHUNK;  // 391
    k_fused<<<ngemm + npart, 256, 0, stream>>>(X, Wt, Y0, N, NB, fflag,
                                               EI, E, flag, bucket, gcur, npart);

    k_build<<<NB, 256, 0, stream>>>(bucket, gcur, cnt, dinv, ellu,
                                    (const unsigned int*)Y0, (unsigned int*)Z0, N);

    const int nb_h = (N + 7) / 8;  // 6250
    k_hop<<<nb_h, 256, 0, stream>>>((const unsigned int*)Z0, ellu, cnt, dinv,
                                    (unsigned int*)Z1, nullptr, bc, N);
    k_hop<<<nb_h, 256, 0, stream>>>((const unsigned int*)Z1, ellu, cnt, dinv,
                                    (unsigned int*)Z0, nullptr, bc, N);
    k_hop<<<nb_h, 256, 0, stream>>>((const unsigned int*)Z0, ellu, cnt, dinv,
                                    nullptr, out, bc, N);
}

// Round 8
// 183.731 us; speedup vs baseline: 1.1093x; 1.0305x over previous
//
#include <hip/hip_runtime.h>
#include <hip/hip_bf16.h>

// SGC: out = (D^-1/2 (A+I) D^-1/2)^3 X W + b
// R18: coalesced B-fragment loads via fragment-ordered Wt (WtF).
//   R16/R17 post-mortem: LDS-free GEMM read B direct from Wt with lanes
//   512B apart -> 64 scattered 64B granules PER INSTRUCTION (4x overfetch,
//   ~64 requests/instr) — the hidden serializer that LDS staging used to
//   mask. Fix: k_setup writes Wt in EXACT per-lane MFMA consumption order
//   WtF[((ks*4+tile)*64+lane)*8+j] (pure permutation of the R16-verified
//   mapping -> numerics unchanged). GEMM B-load = 1KB contiguous per wave,
//   L2-resident, zero LDS -> 8 blocks/CU; A-row 8-deep prefetch kept.
//   Partition (13KB LDS, PCHUNK 2048) / k_build / k_hop bit-identical to
//   R15/R17 (the verified ~186us pipeline).

#define NFEAT 256
#define NCLS  64
#define ELLW  64       // slots per node; P(deg>=64) ~ 1e-18 for Binomial(E,1/N)
#define NPB   128      // nodes per bucket (dst >> 7)
#define BCAP  4096     // per-bucket edge capacity (mean ~2048, sigma ~45)
#define PCHUNK 2048    // edges per partition block

typedef __attribute__((ext_vector_type(8))) short bf16x8;
typedef __attribute__((ext_vector_type(4))) float f32x4;
typedef __attribute__((ext_vector_type(4))) int   i32x4;
typedef __attribute__((ext_vector_type(4))) unsigned int u32x4;

__device__ __forceinline__ float bf2f(unsigned int u) {
    return __uint_as_float(u << 16);
}
__device__ __forceinline__ float bf2f_hi(unsigned int u) {
    return __uint_as_float(u & 0xffff0000u);
}
__device__ __forceinline__ unsigned short f2bf(float f) {
    unsigned int u = __float_as_uint(f);
    unsigned int r = u + 0x7fffu + ((u >> 16) & 1u);  // RNE
    return (unsigned short)(r >> 16);
}
__device__ __forceinline__ unsigned int pack2bf(float a, float b) {
    return (unsigned int)f2bf(a) | ((unsigned int)f2bf(b) << 16);
}

// ---------- fused setup: block0 edge-dtype detect; block1 float detect +
// ---------- bias convert + gcur zero; blocks 2.. W -> fragment-ordered WtF ----
__global__ void k_setup(const void* ei, int twoE, int nnodes,
                        const unsigned int* __restrict__ x, int nwords,
                        const void* __restrict__ Wg, const void* __restrict__ Bg,
                        int* flag, int* fflag, int* gcur, int NB,
                        unsigned short* __restrict__ Wt, float* __restrict__ bc) {
    __shared__ int acc;
    const int t = threadIdx.x;
    const int b = blockIdx.x;
    if (t == 0) acc = 0;
    __syncthreads();

    if (b == 0) {
        const long long* p = (const long long*)ei;
        int nchk = 2048;
        if (nchk > twoE / 2) nchk = twoE / 2;
        int bad = 0;
        for (int i = t; i < nchk; i += 256) {
            long long v = p[i];
            if (v < 0 || v >= (long long)nnodes) bad++;
        }
        if (bad) atomicAdd(&acc, bad);
        __syncthreads();
        if (t == 0) *flag = (acc == 0) ? 1 : 0;  // 1 = int64
        return;
    }

    // float dtype probe (local to each block; x is same dtype as W/b)
    int lim = nwords < 4096 ? nwords : 4096;
    int wild = 0;
    for (int i = t; i < lim; i += 256) {
        unsigned int lo = x[i] & 0xffffu;
        unsigned int expf = (lo >> 7) & 0xffu;
        if (expf >= 0x97u) wild++;  // fp32 mantissa noise read as bf16
    }
    if (wild) atomicAdd(&acc, wild);
    __syncthreads();
    const bool isbf = (acc < 8);

    if (b == 1) {
        if (t == 0) *fflag = isbf ? 1 : 0;
        for (int i = t; i < NB; i += 256) gcur[i] = 0;
        if (t < NCLS) {
            bc[t] = isbf ? bf2f(((const unsigned short*)Bg)[t])
                         : ((const float*)Bg)[t];
        }
        return;
    }

    // W -> bf16 in FRAGMENT order: WtF[((ks*4+tile)*64+lane)*8+j]
    //   = W[k][n],  n = tile*16 + (lane&15),  k = ks*32 + (lane>>4)*8 + j.
    // Same values as the R16-verified direct mapping — pure permutation.
    int i = (b - 2) * 256 + t;
    if (i < NFEAT * NCLS) {
        int j    = i & 7;
        int lane = (i >> 3) & 63;
        int tt   = (i >> 9) & 3;
        int ks   = i >> 11;
        int n = tt * 16 + (lane & 15);
        int k = ks * 32 + ((lane >> 4) << 3) + j;
        Wt[i] = isbf ? ((const unsigned short*)Wg)[k * NCLS + n]
                     : f2bf(((const float*)Wg)[k * NCLS + n]);
    }
}

// ---------- fused: [0, npart) = partition blocks, [npart, ..) = GEMM ----
// LDS = 13KB (partition stage+hist only); GEMM path uses no LDS.
__launch_bounds__(256)
__global__ void k_fused(const void* __restrict__ Xg,
                        const unsigned short* __restrict__ Wt,  // WtF fragment order
                        unsigned short* __restrict__ Yb,        // out bf16 [N][64]
                        int N, int NB, const int* __restrict__ fflag,
                        const void* __restrict__ ei, int E, const int* __restrict__ flag,
                        unsigned int* __restrict__ bucket, int* __restrict__ gcur,
                        int npart) {
    __shared__ char smem[PCHUNK * 4 + 3 * 1600];  // 13 KB
    const int t = threadIdx.x;

    if (blockIdx.x < npart) {
        // ---------------- partition path ----------------
        unsigned int* stage = (unsigned int*)smem;       // PCHUNK entries
        int* hist = (int*)(smem + PCHUNK * 4);           // [400]
        int* base = hist + 400;
        int* rank = base + 400;
        for (int b = t; b < NB; b += 256) { hist[b] = 0; rank[b] = 0; }
        __syncthreads();
        const int bstart = blockIdx.x * PCHUNK;
        const bool is64 = (*flag != 0);
#pragma unroll
        for (int i = 0; i < PCHUNK / 256; ++i) {
            int e = bstart + i * 256 + t;
            unsigned int v = 0xFFFFFFFFu;  // sentinel
            if (e < E) {
                int ss, dd;
                if (is64) {
                    ss = (int)__builtin_nontemporal_load((const long long*)ei + e);
                    dd = (int)__builtin_nontemporal_load((const long long*)ei + E + e);
                } else {
                    ss = __builtin_nontemporal_load((const int*)ei + e);
                    dd = __builtin_nontemporal_load((const int*)ei + E + e);
                }
                int j = dd >> 7;
                atomicAdd(&hist[j], 1);
                v = ((unsigned int)j << 23) | ((unsigned int)(dd & 127) << 16) |
                    (unsigned int)ss;
            }
            stage[i * 256 + t] = v;
        }
        __syncthreads();
        for (int b = t; b < NB; b += 256) base[b] = atomicAdd(&gcur[b], hist[b]);
        __syncthreads();
#pragma unroll
        for (int i = 0; i < PCHUNK / 256; ++i) {
            unsigned int v = stage[i * 256 + t];
            if (v != 0xFFFFFFFFu) {
                int j = v >> 23;
                int r = atomicAdd(&rank[j], 1);
                int pos = base[j] + r;
                if (pos < BCAP)
                    bucket[(size_t)j * BCAP + pos] = v & 0x7FFFFFu;  // (ld<<16)|s
            }
        }
        return;
    }

    // ---------------- GEMM path (no LDS; B coalesced from WtF) ----
    const int gb = blockIdx.x - npart;
    const int wv = t >> 6, lane = t & 63;
    const int m = lane & 15, q = lane >> 4;
    const int row = gb * 64 + wv * 16 + m;
    const bool rowok = row < N;
    const bool isbf = (*fflag != 0);

    // Preload the lane's whole A-slice: 8 independent loads in flight.
    i32x4 ra[8], rb[8];
    if (rowok) {
        if (isbf) {
#pragma unroll
            for (int ks = 0; ks < 8; ++ks) {
                const i32x4* xp = (const i32x4*)((const unsigned short*)Xg +
                                                 (size_t)row * NFEAT + ks * 32 + q * 8);
                ra[ks] = __builtin_nontemporal_load(xp);
            }
        } else {
#pragma unroll
            for (int ks = 0; ks < 8; ++ks) {
                const i32x4* xp = (const i32x4*)((const float*)Xg +
                                                 (size_t)row * NFEAT + ks * 32 + q * 8);
                ra[ks] = __builtin_nontemporal_load(xp);
                rb[ks] = __builtin_nontemporal_load(xp + 1);
            }
        }
    }

    const bf16x8* __restrict__ wf = (const bf16x8*)Wt;  // fragment order

    f32x4 acc0 = {0.f, 0.f, 0.f, 0.f};
    f32x4 acc1 = {0.f, 0.f, 0.f, 0.f};
    f32x4 acc2 = {0.f, 0.f, 0.f, 0.f};
    f32x4 acc3 = {0.f, 0.f, 0.f, 0.f};

#pragma unroll
    for (int ks = 0; ks < 8; ++ks) {
        bf16x8 af = {0, 0, 0, 0, 0, 0, 0, 0};
        if (rowok) {
            if (isbf) {
                i32x4 raw = ra[ks];
#pragma unroll
                for (int h = 0; h < 4; ++h) {
                    af[2 * h]     = (short)(raw[h] & 0xffff);
                    af[2 * h + 1] = (short)(((unsigned int)raw[h]) >> 16);
                }
            } else {
                i32x4 r0 = ra[ks], r1 = rb[ks];
#pragma unroll
                for (int h = 0; h < 4; ++h) {
                    af[h]     = (short)f2bf(__int_as_float(r0[h]));
                    af[h + 4] = (short)f2bf(__int_as_float(r1[h]));
                }
            }
        }
        // coalesced: 64 lanes x 16B contiguous per (ks,tile)
        bf16x8 b0 = wf[(ks * 4 + 0) * 64 + lane];
        bf16x8 b1 = wf[(ks * 4 + 1) * 64 + lane];
        bf16x8 b2 = wf[(ks * 4 + 2) * 64 + lane];
        bf16x8 b3 = wf[(ks * 4 + 3) * 64 + lane];
        acc0 = __builtin_amdgcn_mfma_f32_16x16x32_bf16(af, b0, acc0, 0, 0, 0);
        acc1 = __builtin_amdgcn_mfma_f32_16x16x32_bf16(af, b1, acc1, 0, 0, 0);
        acc2 = __builtin_amdgcn_mfma_f32_16x16x32_bf16(af, b2, acc2, 0, 0, 0);
        acc3 = __builtin_amdgcn_mfma_f32_16x16x32_bf16(af, b3, acc3, 0, 0, 0);
    }

    // C/D layout: col = lane&15, row = q*4 + reg
    const int rowbase = gb * 64 + wv * 16 + q * 4;
#pragma unroll
    for (int i = 0; i < 4; ++i) {
        int gr = rowbase + i;
        if (gr < N) {
            unsigned short* yp = Yb + (size_t)gr * NCLS + m;
            yp[0]  = f2bf(acc0[i]);
            yp[16] = f2bf(acc1[i]);
            yp[32] = f2bf(acc2[i]);
            yp[48] = f2bf(acc3[i]);
        }
    }
}

// ---------- pass 2: one block per bucket; build 128-node ELL slab in LDS,
// ---------- dump ELL+cnt+dinv coalesced; Z = dinv .* Y (bf16 [N][64]) ----------
__launch_bounds__(256)
__global__ void k_build(const unsigned int* __restrict__ bucket,
                        const int* __restrict__ gcur,
                        int* __restrict__ cnt, float* __restrict__ dinv,
                        unsigned short* __restrict__ ellu,
                        const unsigned int* __restrict__ Yb,  // [N][32] u32 view
                        unsigned int* __restrict__ Z,         // [N][32] u32 view
                        int N) {
    __shared__ unsigned short ellb[NPB * ELLW];  // 16 KB
    __shared__ int lcnt[NPB];
    __shared__ float sdinv[NPB];
    const int t = threadIdx.x;
    const int j = blockIdx.x;
    if (t < NPB) lcnt[t] = 0;
    {
        u32x4* eb4 = (u32x4*)ellb;
        u32x4 z = {0, 0, 0, 0};
        for (int i = t; i < NPB * ELLW / 8; i += 256) eb4[i] = z;
    }
    __syncthreads();
    int total = gcur[j];
    if (total > BCAP) total = BCAP;
    const unsigned int* bb = bucket + (size_t)j * BCAP;
    for (int i = t; i < total; i += 256) {
        unsigned int v = __builtin_nontemporal_load(bb + i);
        int ld = (v >> 16) & 127;
        int s = v & 0xffffu;
        int r = atomicAdd(&lcnt[ld], 1);
        if (r < ELLW) ellb[(ld << 6) + r] = (unsigned short)s;
    }
    __syncthreads();
    const int node0 = j << 7;
    if (t < NPB) {
        int node = node0 + t;
        int c = lcnt[t];
        float dv = rsqrtf((float)(c + 1));  // +1 = self loop
        sdinv[t] = dv;
        if (node < N) {
            cnt[node] = c > ELLW ? ELLW : c;
            dinv[node] = dv;
        }
    }
    __syncthreads();
    // dump ELL slab (u32x4 = 8 entries), rows 128B each
    u32x4* ellg = (u32x4*)ellu;
    const u32x4* eb = (const u32x4*)ellb;
    for (int i = t; i < NPB * (ELLW / 8); i += 256) {
        int node = node0 + (i >> 3);
        if (node < N) ellg[(size_t)node0 * 8 + i] = eb[i];
    }
    // Z = dinv .* Y (u32 = 2 bf16 feats per word)
    for (int w = t; w < NPB * 32; w += 256) {
        int nl = w >> 5, l = w & 31;
        int node = node0 + nl;
        if (node < N) {
            float dv = sdinv[nl];
            unsigned int y = Yb[(size_t)node * 32 + l];
            Z[(size_t)node * 32 + l] = pack2bf(dv * bf2f(y), dv * bf2f_hi(y));
        }
    }
}

// ---------- hop: 32-lane node-groups, lane = feature pair (u32 = 2 bf16) ----
// Zout[d] = dinv_d^2 * (Z[d] + sum_s Z[s]);  last hop: out = dinv_d*(...) + b.
__launch_bounds__(256)
__global__ void k_hop(const unsigned int* __restrict__ Zin,  // [N][32] u32
                      const unsigned short* __restrict__ ellu,
                      const int* __restrict__ cnt, const float* __restrict__ dinv,
                      unsigned int* __restrict__ Zout,       // hops 1-2
                      float* __restrict__ outf,              // last hop [N][64] fp32
                      const float* __restrict__ bc, int N) {
    int node = blockIdx.x * 8 + (threadIdx.x >> 5);
    if (node >= N) return;
    const int l = threadIdx.x & 31;
    const int deg = cnt[node];   // clamped <= 64 by k_build
    const float dn = dinv[node];
    unsigned int zself = Zin[(size_t)node * 32 + l];
    float a0 = bf2f(zself), a1 = 0.f, a2 = 0.f, a3 = 0.f;       // lo chains
    float b0 = bf2f_hi(zself), b1 = 0.f, b2 = 0.f, b3 = 0.f;    // hi chains
    const unsigned short* erow = ellu + (size_t)node * ELLW;
    int e = 0;
    for (; e + 16 <= deg; e += 16) {
        u32x4 ua = *(const u32x4*)(erow + e);      // 8 edges (broadcast 16B)
        u32x4 ub = *(const u32x4*)(erow + e + 8);  // 8 edges
        int s[16];
#pragma unroll
        for (int i = 0; i < 4; ++i) {
            s[2 * i]     = (int)(ua[i] & 0xffffu);
            s[2 * i + 1] = (int)(ua[i] >> 16);
            s[2 * i + 8] = (int)(ub[i] & 0xffffu);
            s[2 * i + 9] = (int)(ub[i] >> 16);
        }
        unsigned int z[16];
#pragma unroll
        for (int i = 0; i < 16; ++i) z[i] = Zin[(size_t)s[i] * 32 + l];
#pragma unroll
        for (int i = 0; i < 16; i += 4) {
            a0 += bf2f(z[i]);     b0 += bf2f_hi(z[i]);
            a1 += bf2f(z[i + 1]); b1 += bf2f_hi(z[i + 1]);
            a2 += bf2f(z[i + 2]); b2 += bf2f_hi(z[i + 2]);
            a3 += bf2f(z[i + 3]); b3 += bf2f_hi(z[i + 3]);
        }
    }
    if (e < deg) {  // guarded tail batch; ELL tail is zeroed -> s=0 reads safe
        u32x4 ua = *(const u32x4*)(erow + e);
        u32x4 ub = *(const u32x4*)(erow + e + 8);
        int s[16];
#pragma unroll
        for (int i = 0; i < 4; ++i) {
            s[2 * i]     = (int)(ua[i] & 0xffffu);
            s[2 * i + 1] = (int)(ua[i] >> 16);
            s[2 * i + 8] = (int)(ub[i] & 0xffffu);
            s[2 * i + 9] = (int)(ub[i] >> 16);
        }
        unsigned int z[16];
#pragma unroll
        for (int i = 0; i < 16; ++i) z[i] = Zin[(size_t)s[i] * 32 + l];
#pragma unroll
        for (int i = 0; i < 16; i += 4) {
            bool g0 = (e + i < deg), g1 = (e + i + 1 < deg);
            bool g2 = (e + i + 2 < deg), g3 = (e + i + 3 < deg);
            a0 += g0 ? bf2f(z[i]) : 0.f;     b0 += g0 ? bf2f_hi(z[i]) : 0.f;
            a1 += g1 ? bf2f(z[i + 1]) : 0.f; b1 += g1 ? bf2f_hi(z[i + 1]) : 0.f;
            a2 += g2 ? bf2f(z[i + 2]) : 0.f; b2 += g2 ? bf2f_hi(z[i + 2]) : 0.f;
            a3 += g3 ? bf2f(z[i + 3]) : 0.f; b3 += g3 ? bf2f_hi(z[i + 3]) : 0.f;
        }
    }
    float lo = (a0 + a1) + (a2 + a3);
    float hi = (b0 + b1) + (b2 + b3);
    if (outf) {
        float2 bv = *(const float2*)(bc + 2 * l);
        float2 o = make_float2(dn * lo + bv.x, dn * hi + bv.y);
        *(float2*)(outf + (size_t)node * NCLS + 2 * l) = o;
    } else {
        float d2 = dn * dn;
        Zout[(size_t)node * 32 + l] = pack2bf(d2 * lo, d2 * hi);
    }
}

extern "C" void kernel_launch(void* const* d_in, const int* in_sizes, int n_in,
                              void* d_out, int out_size, void* d_ws, size_t ws_size,
                              hipStream_t stream) {
    const void* X  = d_in[0];
    const void* EI = d_in[1];
    const void* W  = d_in[2];
    const void* B  = d_in[3];
    float* out = (float*)d_out;

    const int N = in_sizes[0] / NFEAT;  // 50000
    const int twoE = in_sizes[1];       // 1,600,000
    const int E = twoE / 2;             // 800,000
    const int NB = (N + NPB - 1) / NPB; // 391 buckets

    // ---- carve workspace (256B aligned) ----
    char* p = (char*)d_ws;
    auto alloc = [&](size_t bytes) -> char* {
        char* q = p;
        p += (bytes + 255) & ~(size_t)255;
        return q;
    };
    int*   flag   = (int*)alloc(4);
    int*   fflag  = (int*)alloc(4);
    int*   gcur   = (int*)alloc((size_t)NB * 4);
    int*   cnt    = (int*)alloc((size_t)N * 4);
    float* dinv   = (float*)alloc((size_t)N * 4);
    unsigned short* Wt = (unsigned short*)alloc((size_t)NFEAT * NCLS * 2);
    float* bc     = (float*)alloc((size_t)NCLS * 4);
    unsigned int* bucket = (unsigned int*)alloc((size_t)NB * BCAP * 4);   // 6.4 MB
    unsigned short* ellu = (unsigned short*)alloc((size_t)N * ELLW * 2);  // 6.4 MB
    unsigned short* Y0 = (unsigned short*)alloc((size_t)N * NCLS * 2);    // 6.4 MB
    unsigned short* Z0 = (unsigned short*)alloc((size_t)N * NCLS * 2);    // 6.4 MB
    unsigned short* Z1 = (unsigned short*)alloc((size_t)N * NCLS * 2);    // 6.4 MB

    k_setup<<<2 + NFEAT * NCLS / 256, 256, 0, stream>>>(
        EI, twoE, N, (const unsigned int*)X, in_sizes[0] / 2,
        W, B, flag, fflag, gcur, NB, Wt, bc);

    const int ngemm = (N + 63) / 64;              // 782
    const int npart = (E + PCHUNK - 1) / PCHUNK;  // 391
    k_fused<<<ngemm + npart, 256, 0, stream>>>(X, Wt, Y0, N, NB, fflag,
                                               EI, E, flag, bucket, gcur, npart);

    k_build<<<NB, 256, 0, stream>>>(bucket, gcur, cnt, dinv, ellu,
                                    (const unsigned int*)Y0, (unsigned int*)Z0, N);

    const int nb_h = (N + 7) / 8;  // 6250
    k_hop<<<nb_h, 256, 0, stream>>>((const unsigned int*)Z0, ellu, cnt, dinv,
                                    (unsigned int*)Z1, nullptr, bc, N);
    k_hop<<<nb_h, 256, 0, stream>>>((const unsigned int*)Z1, ellu, cnt, dinv,
                                    (unsigned int*)Z0, nullptr, bc, N);
    k_hop<<<nb_h, 256, 0, stream>>>((const unsigned int*)Z0, ellu, cnt, dinv,
                                    nullptr, out, bc, N);
}